// Round 6
// baseline (108.144 us; speedup 1.0000x reference)
//
#include <hip/hip_runtime.h>
#include <math.h>

#define NCELL (32768 * 49)   // 1,605,632
#define NE 30
#define NC 20                // classes
#define BLK 256
#define CPB 512              // contiguous cells per block (2 per thread)
#define G1 3136              // 3136 * 512 == NCELL exactly (no tail)

// ws layout: [0..255] u32 done-counter (zeroed per call via hipMemsetAsync);
//            [256...] float partial[G1*6] (fully written before counted).

__device__ __forceinline__ void process_cell(
    const float* __restrict__ pred, const float* __restrict__ targ, int cell,
    float& a0, float& a1, float& a2, float& a3, float& a4, float& a5) {

    const float2* p2 = reinterpret_cast<const float2*>(pred + (size_t)cell * NE);
    const float2* t2 = reinterpret_cast<const float2*>(targ + (size_t)cell * NE);

    float p[30], t[12];
    #pragma unroll
    for (int i = 0; i < 15; ++i) { float2 v = p2[i]; p[2*i] = v.x; p[2*i+1] = v.y; }
    #pragma unroll
    for (int i = 0; i < 6; ++i)  { float2 v = t2[i]; t[2*i] = v.x; t[2*i+1] = v.y; }

    // 2x2 cross IoU between pred boxes (rows) and target boxes (cols)
    float iou[2][2];
    #pragma unroll
    for (int i = 0; i < 2; ++i) {
        const float pcx = p[5*i], pcy = p[5*i+1], pw = p[5*i+2], ph = p[5*i+3];
        const float alx = pcx - pw*0.5f, aly = pcy - ph*0.5f;
        const float ahx = pcx + pw*0.5f, ahy = pcy + ph*0.5f;
        const float area_a = pw * ph;
        #pragma unroll
        for (int j = 0; j < 2; ++j) {
            const float tcx = t[5*j], tcy = t[5*j+1], tw = t[5*j+2], th = t[5*j+3];
            const float blx = tcx - tw*0.5f, bly = tcy - th*0.5f;
            const float bhx = tcx + tw*0.5f, bhy = tcy + th*0.5f;
            float ix = fminf(ahx, bhx) - fmaxf(alx, blx);
            float iy = fminf(ahy, bhy) - fmaxf(aly, bly);
            ix = fmaxf(ix, 0.f); iy = fmaxf(iy, 0.f);
            const float inter = ix * iy;
            const float area_b = tw * th;
            iou[i][j] = inter / (area_a + area_b - inter + 1e-12f);
        }
    }
    // argmax over pred-box axis, first-occurrence tie break (index 0)
    const int idx0 = (iou[1][0] > iou[0][0]) ? 1 : 0;
    const int idx1 = (iou[1][1] > iou[0][1]) ? 1 : 0;

    #pragma unroll
    for (int k = 0; k < 2; ++k) {
        const bool resp = (idx0 == k || idx1 == k);
        if (resp) {
            a0 += 1.f;
            const float cp = p[5*k+4], ct = t[5*k+4];
            // logaddexp(0, cp) - cp*ct  (stable)
            a1 += fmaxf(cp, 0.f) + log1pf(expf(-fabsf(cp))) - cp * ct;
            const float dx = p[5*k]   - t[5*k];
            const float dy = p[5*k+1] - t[5*k+1];
            a2 += dx*dx + dy*dy;
            const float dw = p[5*k+2] - t[5*k+2];
            const float dh = p[5*k+3] - t[5*k+3];
            a3 += dw*dw + dh*dh;
        }
    }

    a5 += 1.f;
    // class index: clip(floor(t10), 0, 19)  (clip in float, then cast)
    const float cf = fminf(fmaxf(floorf(t[10]), 0.f), 19.f);
    const int cls = (int)cf;
    float m = p[10];
    #pragma unroll
    for (int c = 1; c < NC; ++c) m = fmaxf(m, p[10 + c]);
    float se = 0.f;
    float sel = 0.f;   // p[10+cls] via static-index select (no scratch)
    #pragma unroll
    for (int c = 0; c < NC; ++c) {
        se += expf(p[10 + c] - m);
        sel += (c == cls) ? p[10 + c] : 0.f;
    }
    a4 += -(sel - m - logf(se));
}

__global__ __launch_bounds__(BLK) void yolo_fused(
    const float* __restrict__ pred,
    const float* __restrict__ targ,
    unsigned int* __restrict__ counter,
    float* __restrict__ partial,
    float* __restrict__ out) {

    const int base = blockIdx.x * CPB;
    const int tid  = threadIdx.x;
    const int wave = tid >> 6;
    const int lane = tid & 63;

    // --- scan: 2 t4 loads per thread, issued upfront ---
    float t4a = targ[(size_t)(base + tid)       * NE + 4];
    float t4b = targ[(size_t)(base + BLK + tid) * NE + 4];

    // --- ballot-compact coord cells into per-wave LDS segments ---
    __shared__ int s_idx[4][128];
    __shared__ int s_cnt[4];
    int cnt = 0;
    {
        const bool c = t4a > 0.f;
        const unsigned long long m = __ballot(c);
        const int pre = __popcll(m & ((1ull << lane) - 1ull));
        if (c) s_idx[wave][pre] = tid;
        cnt = __popcll(m);
    }
    {
        const bool c = t4b > 0.f;
        const unsigned long long m = __ballot(c);
        const int pre = __popcll(m & ((1ull << lane) - 1ull));
        if (c) s_idx[wave][cnt + pre] = BLK + tid;
        cnt += __popcll(m);
    }
    if (lane == 0) s_cnt[wave] = cnt;
    __syncthreads();

    const int c0 = s_cnt[0], c1 = s_cnt[1], c2 = s_cnt[2], c3 = s_cnt[3];
    const int total = c0 + c1 + c2 + c3;   // ~42 avg of 512

    float a0 = 0.f, a1 = 0.f, a2 = 0.f, a3 = 0.f, a4 = 0.f, a5 = 0.f;

    // --- dense heavy pass (normally a single iteration) ---
    for (int i = tid; i < total; i += BLK) {
        int j = i, w = 0;
        if (j >= c0) { j -= c0; w = 1;
            if (j >= c1) { j -= c1; w = 2;
                if (j >= c2) { j -= c2; w = 3; } } }
        process_cell(pred, targ, base + s_idx[w][j], a0, a1, a2, a3, a4, a5);
    }

    // --- wave tree reduction ---
    #pragma unroll
    for (int off = 32; off > 0; off >>= 1) {
        a0 += __shfl_down(a0, off, 64);
        a1 += __shfl_down(a1, off, 64);
        a2 += __shfl_down(a2, off, 64);
        a3 += __shfl_down(a3, off, 64);
        a4 += __shfl_down(a4, off, 64);
        a5 += __shfl_down(a5, off, 64);
    }

    __shared__ float sm[4][6];
    __shared__ int s_is_last;
    if (lane == 0) {
        sm[wave][0] = a0; sm[wave][1] = a1; sm[wave][2] = a2;
        sm[wave][3] = a3; sm[wave][4] = a4; sm[wave][5] = a5;
    }
    __syncthreads();
    if (tid == 0) {
        // release-publish this block's 6 partials, then count
        #pragma unroll
        for (int k = 0; k < 6; ++k) {
            float s = sm[0][k] + sm[1][k] + sm[2][k] + sm[3][k];
            __hip_atomic_store(&partial[blockIdx.x * 6 + k], s,
                               __ATOMIC_RELAXED, __HIP_MEMORY_SCOPE_AGENT);
        }
        unsigned int old = __hip_atomic_fetch_add(counter, 1u,
                               __ATOMIC_ACQ_REL, __HIP_MEMORY_SCOPE_AGENT);
        s_is_last = (old == (unsigned int)(G1 - 1));
    }
    __syncthreads();

    if (s_is_last) {
        // last arriving block: all G1 partials are published (each producer's
        // release precedes its count; our acquire saw the final count).
        double a[6] = {0, 0, 0, 0, 0, 0};
        for (int i = tid; i < G1; i += BLK) {
            #pragma unroll
            for (int k = 0; k < 6; ++k)
                a[k] += (double)__hip_atomic_load(&partial[i * 6 + k],
                            __ATOMIC_RELAXED, __HIP_MEMORY_SCOPE_AGENT);
        }
        __shared__ double sd[BLK][6];
        #pragma unroll
        for (int k = 0; k < 6; ++k) sd[tid][k] = a[k];
        __syncthreads();
        for (int off = BLK / 2; off > 0; off >>= 1) {
            if (tid < off) {
                #pragma unroll
                for (int k = 0; k < 6; ++k) sd[tid][k] += sd[tid + off][k];
            }
            __syncthreads();
        }
        if (tid == 0) {
            const double resp_sum  = sd[0][0];
            const double bce_sum   = sd[0][1];
            const double sqxy_sum  = sd[0][2];
            const double sqwh_sum  = sd[0][3];
            const double nll_sum   = sd[0][4];
            const double coord_sum = sd[0][5];
            const double cnt_d = fmax(resp_sum, 1.0);
            const double contain_loss = bce_sum / cnt_d;
            const double loc_loss = (sqxy_sum + sqwh_sum) / (2.0 * cnt_d);
            const double class_loss = nll_sum / fmax(coord_sum, 1.0);
            out[0] = (float)(class_loss + contain_loss + 5.0 * loc_loss);
        }
    }
}

extern "C" void kernel_launch(void* const* d_in, const int* in_sizes, int n_in,
                              void* d_out, int out_size, void* d_ws, size_t ws_size,
                              hipStream_t stream) {
    const float* pred = (const float*)d_in[0];
    const float* targ = (const float*)d_in[1];
    unsigned int* counter = (unsigned int*)d_ws;
    float* partial = (float*)((char*)d_ws + 256);

    // zero the done-counter each call (captured into the graph -> every replay)
    hipMemsetAsync(d_ws, 0, 256, stream);
    yolo_fused<<<G1, BLK, 0, stream>>>(pred, targ, counter, partial, (float*)d_out);
}

// Round 7
// 47.763 us; speedup vs baseline: 2.2642x; 2.2642x over previous
//
#include <hip/hip_runtime.h>
#include <math.h>

#define NCELL (32768 * 49)   // 1,605,632
#define NE 30
#define NC 20                // classes
#define BLK 256
#define CPB 512              // contiguous cells per block (2 per thread)
#define G1 3136              // 3136 * 512 == NCELL exactly (no tail)

// partial layout per block: [resp_sum, bce_sum, sqxy_sum, sqwh_sum, nll_sum, coord_sum]

__device__ __forceinline__ void process_cell(
    const float* __restrict__ pred, const float* __restrict__ targ, int cell,
    float& a0, float& a1, float& a2, float& a3, float& a4, float& a5) {

    const float2* p2 = reinterpret_cast<const float2*>(pred + (size_t)cell * NE);
    const float2* t2 = reinterpret_cast<const float2*>(targ + (size_t)cell * NE);

    float p[30], t[12];
    #pragma unroll
    for (int i = 0; i < 15; ++i) { float2 v = p2[i]; p[2*i] = v.x; p[2*i+1] = v.y; }
    #pragma unroll
    for (int i = 0; i < 6; ++i)  { float2 v = t2[i]; t[2*i] = v.x; t[2*i+1] = v.y; }

    // 2x2 cross IoU between pred boxes (rows) and target boxes (cols)
    float iou[2][2];
    #pragma unroll
    for (int i = 0; i < 2; ++i) {
        const float pcx = p[5*i], pcy = p[5*i+1], pw = p[5*i+2], ph = p[5*i+3];
        const float alx = pcx - pw*0.5f, aly = pcy - ph*0.5f;
        const float ahx = pcx + pw*0.5f, ahy = pcy + ph*0.5f;
        const float area_a = pw * ph;
        #pragma unroll
        for (int j = 0; j < 2; ++j) {
            const float tcx = t[5*j], tcy = t[5*j+1], tw = t[5*j+2], th = t[5*j+3];
            const float blx = tcx - tw*0.5f, bly = tcy - th*0.5f;
            const float bhx = tcx + tw*0.5f, bhy = tcy + th*0.5f;
            float ix = fminf(ahx, bhx) - fmaxf(alx, blx);
            float iy = fminf(ahy, bhy) - fmaxf(aly, bly);
            ix = fmaxf(ix, 0.f); iy = fmaxf(iy, 0.f);
            const float inter = ix * iy;
            const float area_b = tw * th;
            iou[i][j] = inter / (area_a + area_b - inter + 1e-12f);
        }
    }
    // argmax over pred-box axis, first-occurrence tie break (index 0)
    const int idx0 = (iou[1][0] > iou[0][0]) ? 1 : 0;
    const int idx1 = (iou[1][1] > iou[0][1]) ? 1 : 0;

    #pragma unroll
    for (int k = 0; k < 2; ++k) {
        const bool resp = (idx0 == k || idx1 == k);
        if (resp) {
            a0 += 1.f;
            const float cp = p[5*k+4], ct = t[5*k+4];
            // logaddexp(0, cp) - cp*ct  (stable)
            a1 += fmaxf(cp, 0.f) + log1pf(expf(-fabsf(cp))) - cp * ct;
            const float dx = p[5*k]   - t[5*k];
            const float dy = p[5*k+1] - t[5*k+1];
            a2 += dx*dx + dy*dy;
            const float dw = p[5*k+2] - t[5*k+2];
            const float dh = p[5*k+3] - t[5*k+3];
            a3 += dw*dw + dh*dh;
        }
    }

    a5 += 1.f;
    // class index: clip(floor(t10), 0, 19)  (clip in float, then cast)
    const float cf = fminf(fmaxf(floorf(t[10]), 0.f), 19.f);
    const int cls = (int)cf;
    float m = p[10];
    #pragma unroll
    for (int c = 1; c < NC; ++c) m = fmaxf(m, p[10 + c]);
    float se = 0.f;
    float sel = 0.f;   // p[10+cls] via static-index select (no scratch)
    #pragma unroll
    for (int c = 0; c < NC; ++c) {
        se += expf(p[10 + c] - m);
        sel += (c == cls) ? p[10 + c] : 0.f;
    }
    a4 += -(sel - m - logf(se));
}

__global__ __launch_bounds__(BLK) void yolo_partial(
    const float* __restrict__ pred,
    const float* __restrict__ targ,
    float* __restrict__ partial) {

    const int base = blockIdx.x * CPB;
    const int tid  = threadIdx.x;
    const int wave = tid >> 6;
    const int lane = tid & 63;

    // --- scan: 2 t4 loads per thread, issued upfront ---
    const float t4a = targ[(size_t)(base + tid)       * NE + 4];
    const float t4b = targ[(size_t)(base + BLK + tid) * NE + 4];

    // --- ballot-compact coord cells into per-wave LDS segments ---
    // (deterministic: fixed ballot -> prefix order, no atomics)
    __shared__ int s_idx[4][128];
    __shared__ int s_cnt[4];
    int cnt = 0;
    {
        const bool c = t4a > 0.f;
        const unsigned long long m = __ballot(c);
        const int pre = __popcll(m & ((1ull << lane) - 1ull));
        if (c) s_idx[wave][pre] = tid;
        cnt = __popcll(m);
    }
    {
        const bool c = t4b > 0.f;
        const unsigned long long m = __ballot(c);
        const int pre = __popcll(m & ((1ull << lane) - 1ull));
        if (c) s_idx[wave][cnt + pre] = BLK + tid;
        cnt += __popcll(m);
    }
    if (lane == 0) s_cnt[wave] = cnt;
    __syncthreads();

    const int c0 = s_cnt[0], c1 = s_cnt[1], c2 = s_cnt[2], c3 = s_cnt[3];
    const int total = c0 + c1 + c2 + c3;   // ~42 avg of 512

    float a0 = 0.f, a1 = 0.f, a2 = 0.f, a3 = 0.f, a4 = 0.f, a5 = 0.f;

    // --- dense heavy pass (normally a single iteration) ---
    for (int i = tid; i < total; i += BLK) {
        int j = i, w = 0;
        if (j >= c0) { j -= c0; w = 1;
            if (j >= c1) { j -= c1; w = 2;
                if (j >= c2) { j -= c2; w = 3; } } }
        process_cell(pred, targ, base + s_idx[w][j], a0, a1, a2, a3, a4, a5);
    }

    // --- wave tree reduction ---
    #pragma unroll
    for (int off = 32; off > 0; off >>= 1) {
        a0 += __shfl_down(a0, off, 64);
        a1 += __shfl_down(a1, off, 64);
        a2 += __shfl_down(a2, off, 64);
        a3 += __shfl_down(a3, off, 64);
        a4 += __shfl_down(a4, off, 64);
        a5 += __shfl_down(a5, off, 64);
    }

    __shared__ float sm[4][6];
    if (lane == 0) {
        sm[wave][0] = a0; sm[wave][1] = a1; sm[wave][2] = a2;
        sm[wave][3] = a3; sm[wave][4] = a4; sm[wave][5] = a5;
    }
    __syncthreads();
    if (tid == 0) {
        #pragma unroll
        for (int k = 0; k < 6; ++k) {
            // fixed-order sum over the 4 waves -> deterministic
            float s = sm[0][k] + sm[1][k] + sm[2][k] + sm[3][k];
            partial[blockIdx.x * 6 + k] = s;
        }
    }
}

__global__ __launch_bounds__(BLK) void yolo_final(
    const float* __restrict__ partial, float* __restrict__ out) {
    __shared__ double sm[BLK][6];
    double a[6] = {0, 0, 0, 0, 0, 0};
    for (int i = threadIdx.x; i < G1; i += BLK) {
        #pragma unroll
        for (int k = 0; k < 6; ++k) a[k] += (double)partial[i * 6 + k];
    }
    #pragma unroll
    for (int k = 0; k < 6; ++k) sm[threadIdx.x][k] = a[k];
    __syncthreads();
    for (int off = BLK / 2; off > 0; off >>= 1) {
        if (threadIdx.x < off) {
            #pragma unroll
            for (int k = 0; k < 6; ++k) sm[threadIdx.x][k] += sm[threadIdx.x + off][k];
        }
        __syncthreads();
    }
    if (threadIdx.x == 0) {
        const double resp_sum  = sm[0][0];
        const double bce_sum   = sm[0][1];
        const double sqxy_sum  = sm[0][2];
        const double sqwh_sum  = sm[0][3];
        const double nll_sum   = sm[0][4];
        const double coord_sum = sm[0][5];
        const double cnt = fmax(resp_sum, 1.0);
        const double contain_loss = bce_sum / cnt;
        const double loc_loss = (sqxy_sum + sqwh_sum) / (2.0 * cnt);
        const double class_loss = nll_sum / fmax(coord_sum, 1.0);
        out[0] = (float)(class_loss + contain_loss + 5.0 * loc_loss);
    }
}

extern "C" void kernel_launch(void* const* d_in, const int* in_sizes, int n_in,
                              void* d_out, int out_size, void* d_ws, size_t ws_size,
                              hipStream_t stream) {
    const float* pred = (const float*)d_in[0];
    const float* targ = (const float*)d_in[1];
    float* partial = (float*)d_ws;   // G1*6 floats = 75 KiB

    yolo_partial<<<G1, BLK, 0, stream>>>(pred, targ, partial);
    yolo_final<<<1, BLK, 0, stream>>>(partial, (float*)d_out);
}